// Round 1
// baseline (497.178 us; speedup 1.0000x reference)
//
#include <hip/hip_runtime.h>
#include <hip/hip_bf16.h>
#include <math.h>

#define HIDDEN 512
#define ATTEN  512
#define BATCH  32
#define STEP   2048

#define TM 32                 // positions per block in scores kernel
#define NCH 16                // s-chunks in weighted-sum kernel
#define CHS (STEP / NCH)      // 128 positions per chunk

// batch_lens may arrive as int64 (reference dtype) or int32 (jax without x64).
// Values are always >= 1, so for little-endian int64 the odd int32 word
// (high half of element 0) is 0; for int32 it's batch_lens[1] >= 1.
__device__ __forceinline__ long long load_len(const int* lens_raw, int b) {
    bool is64 = (lens_raw[1] == 0);
    if (is64) return ((const long long*)lens_raw)[b];
    return (long long)lens_raw[b];
}

// K1: scores[b,s] = sum_a tanh( X[b,s,:]·W[:,a] + bias[a] ) * ctx[a]
// One block = 32 positions x all 512 atten columns. Skips fully-masked tiles.
__global__ __launch_bounds__(256) void scores_kernel(
    const float* __restrict__ X,        // [B*S*H]
    const int*   __restrict__ lens_raw,
    const float* __restrict__ W,        // [H*A] row-major
    const float* __restrict__ bias,     // [A]
    const float* __restrict__ ctx,      // [A]
    float* __restrict__ scores)         // [B*S]
{
    __shared__ float xs[TM][HIDDEN];    // 64 KB (exactly the static limit)

    const int tiles_per_b = STEP / TM;  // 64
    int bid = blockIdx.x;
    int b   = bid / tiles_per_b;
    int s0  = (bid % tiles_per_b) * TM;
    long long len = load_len(lens_raw, b);
    if ((long long)s0 >= len) return;   // softmax weight is 0 for all of these

    int t = threadIdx.x;

    // stage X tile [32 x 512] fp32 into LDS, coalesced float4
    const float4* xsrc = (const float4*)(X + ((size_t)b * STEP + s0) * HIDDEN);
    float4* xdst = (float4*)&xs[0][0];
#pragma unroll
    for (int k = 0; k < (TM * HIDDEN) / (256 * 4); ++k) {   // 16 iters
        int f4 = t + k * 256;
        xdst[f4] = xsrc[f4];
    }
    __syncthreads();

    const int c0 = t;        // this thread's two atten columns
    const int c1 = t + 256;

    float acc0[TM], acc1[TM];
#pragma unroll
    for (int m = 0; m < TM; ++m) { acc0[m] = 0.f; acc1[m] = 0.f; }

    for (int hb = 0; hb < HIDDEN; hb += 4) {
        float w00 = W[(hb + 0) * ATTEN + c0];
        float w01 = W[(hb + 1) * ATTEN + c0];
        float w02 = W[(hb + 2) * ATTEN + c0];
        float w03 = W[(hb + 3) * ATTEN + c0];
        float w10 = W[(hb + 0) * ATTEN + c1];
        float w11 = W[(hb + 1) * ATTEN + c1];
        float w12 = W[(hb + 2) * ATTEN + c1];
        float w13 = W[(hb + 3) * ATTEN + c1];
#pragma unroll
        for (int m = 0; m < TM; ++m) {
            float4 xv = *(const float4*)&xs[m][hb];   // uniform addr -> broadcast
            float a0 = acc0[m], a1 = acc1[m];
            a0 = fmaf(xv.x, w00, a0); a0 = fmaf(xv.y, w01, a0);
            a0 = fmaf(xv.z, w02, a0); a0 = fmaf(xv.w, w03, a0);
            a1 = fmaf(xv.x, w10, a1); a1 = fmaf(xv.y, w11, a1);
            a1 = fmaf(xv.z, w12, a1); a1 = fmaf(xv.w, w13, a1);
            acc0[m] = a0; acc1[m] = a1;
        }
    }

    float b0 = bias[c0], b1 = bias[c1];
    float g0 = ctx[c0],  g1 = ctx[c1];
    float sc[TM];
#pragma unroll
    for (int m = 0; m < TM; ++m) {
        sc[m] = tanhf(acc0[m] + b0) * g0 + tanhf(acc1[m] + b1) * g1;
    }

    // full-wave butterfly reduce: every lane ends with the wave total per m
#pragma unroll
    for (int m = 0; m < TM; ++m) {
        float v = sc[m];
        v += __shfl_xor(v, 1);
        v += __shfl_xor(v, 2);
        v += __shfl_xor(v, 4);
        v += __shfl_xor(v, 8);
        v += __shfl_xor(v, 16);
        v += __shfl_xor(v, 32);
        sc[m] = v;
    }

    int wave = t >> 6, lane = t & 63;
    __syncthreads();                          // done reading xs; reuse as scratch
    float* part = (float*)&xs[0][0];          // part[wave*TM + m], 4*32 floats
#pragma unroll
    for (int m = 0; m < TM; ++m) {            // static indexing (no reg spill)
        if (lane == m) part[wave * TM + m] = sc[m];
    }
    __syncthreads();
    if (t < TM) {
        float v = part[0 * TM + t] + part[1 * TM + t]
                + part[2 * TM + t] + part[3 * TM + t];
        scores[(size_t)b * STEP + s0 + t] = v;
    }
}

// K2: masked softmax per batch row (deterministic tree reductions)
__global__ __launch_bounds__(256) void softmax_kernel(
    const float* __restrict__ scores, const int* __restrict__ lens_raw,
    float* __restrict__ atten)
{
    __shared__ float wmax[4], wsum[4];
    int b = blockIdx.x;
    long long len = load_len(lens_raw, b);
    int t = threadIdx.x;
    const float* srow = scores + (size_t)b * STEP;
    float* arow = atten + (size_t)b * STEP;

    float sv[STEP / 256];   // 8
    float locmax = -INFINITY;
#pragma unroll
    for (int k = 0; k < 8; ++k) {
        int s = t + k * 256;
        float v = ((long long)s < len) ? srow[s] : -INFINITY;
        sv[k] = v;
        locmax = fmaxf(locmax, v);
    }
    for (int o = 1; o < 64; o <<= 1) locmax = fmaxf(locmax, __shfl_xor(locmax, o));
    int wave = t >> 6, lane = t & 63;
    if (lane == 0) wmax[wave] = locmax;
    __syncthreads();
    float gmax = fmaxf(fmaxf(wmax[0], wmax[1]), fmaxf(wmax[2], wmax[3]));

    float ev[8];
    float locsum = 0.f;
#pragma unroll
    for (int k = 0; k < 8; ++k) {
        float e = (sv[k] == -INFINITY) ? 0.f : expf(sv[k] - gmax);
        ev[k] = e;
        locsum += e;
    }
    for (int o = 1; o < 64; o <<= 1) locsum += __shfl_xor(locsum, o);
    if (lane == 0) wsum[wave] = locsum;
    __syncthreads();
    float inv = 1.f / (wsum[0] + wsum[1] + wsum[2] + wsum[3]);
#pragma unroll
    for (int k = 0; k < 8; ++k) {
        int s = t + k * 256;
        arow[s] = ev[k] * inv;    // padded positions get exact 0
    }
}

// K3a: partial[b,ch,h] = sum_{s in chunk, s<len} atten[b,s] * X[b,s,h]
__global__ __launch_bounds__(256) void wsum_kernel(
    const float* __restrict__ X, const int* __restrict__ lens_raw,
    const float* __restrict__ atten, float* __restrict__ partial)
{
    int ch = blockIdx.x;     // 0..NCH-1
    int b  = blockIdx.y;     // 0..BATCH-1
    long long len = load_len(lens_raw, b);
    int t = threadIdx.x;
    int s0 = ch * CHS;
    long long send_ll = (long long)(s0 + CHS);
    if (send_ll > len) send_ll = len;
    int send = (int)send_ll;

    const float* arow = atten + (size_t)b * STEP;
    float acc0 = 0.f, acc1 = 0.f;
    for (int s = s0; s < send; ++s) {
        float a = arow[s];
        const float* xr = X + ((size_t)b * STEP + s) * HIDDEN;
        acc0 = fmaf(a, xr[t], acc0);
        acc1 = fmaf(a, xr[t + 256], acc1);
    }
    float* prow = partial + ((size_t)b * NCH + ch) * HIDDEN;
    prow[t] = acc0;            // skipped chunks write zeros (ws is poisoned)
    prow[t + 256] = acc1;
}

// K3b: out[b,h] = sum_ch partial[b,ch,h]
__global__ __launch_bounds__(256) void finalize_kernel(
    const float* __restrict__ partial, float* __restrict__ out)
{
    int b = blockIdx.x;
    int t = threadIdx.x;
    float a0 = 0.f, a1 = 0.f;
#pragma unroll
    for (int ch = 0; ch < NCH; ++ch) {
        const float* prow = partial + ((size_t)b * NCH + ch) * HIDDEN;
        a0 += prow[t];
        a1 += prow[t + 256];
    }
    out[(size_t)b * HIDDEN + t] = a0;
    out[(size_t)b * HIDDEN + t + 256] = a1;
}

extern "C" void kernel_launch(void* const* d_in, const int* in_sizes, int n_in,
                              void* d_out, int out_size, void* d_ws, size_t ws_size,
                              hipStream_t stream) {
    const float* X    = (const float*)d_in[0];
    const int*   lens = (const int*)d_in[1];   // dtype sniffed on device
    const float* W    = (const float*)d_in[2];
    const float* bias = (const float*)d_in[3];
    const float* ctx  = (const float*)d_in[4];
    float* out = (float*)d_out;

    float* scores  = (float*)d_ws;                    // 32*2048 fp32
    float* atten   = scores + BATCH * STEP;           // 32*2048 fp32
    float* partial = atten + BATCH * STEP;            // 32*16*512 fp32

    scores_kernel<<<dim3(BATCH * (STEP / TM)), 256, 0, stream>>>(
        X, lens, W, bias, ctx, scores);
    softmax_kernel<<<dim3(BATCH), 256, 0, stream>>>(scores, lens, atten);
    wsum_kernel<<<dim3(NCH, BATCH), 256, 0, stream>>>(X, lens, atten, partial);
    finalize_kernel<<<dim3(BATCH), 256, 0, stream>>>(partial, out);
}

// Round 2
// 222.476 us; speedup vs baseline: 2.2347x; 2.2347x over previous
//
#include <hip/hip_runtime.h>
#include <hip/hip_bf16.h>
#include <math.h>

#define HIDDEN 512
#define ATTEN  512
#define BATCH  32
#define STEP   2048

#define BM 128                // rows (positions) per scores block
#define BK 128                // K tile
#define THREADS 512           // 8 waves: 2 (M) x 4 (N)

#define NCH 16                // s-chunks in weighted-sum kernel
#define CHS (STEP / NCH)      // 128 positions per chunk

typedef __attribute__((ext_vector_type(8))) short bf16x8;
typedef __attribute__((ext_vector_type(4))) float f32x4;

// batch_lens may arrive as int64 (reference dtype) or int32 (jax without x64).
// Values are always >= 1, so for little-endian int64 the high word of elem 0
// (int32 view index 1) is 0; for int32 it's batch_lens[1] >= 1.
__device__ __forceinline__ long long load_len(const int* lens_raw, int b) {
    bool is64 = (lens_raw[1] == 0);
    if (is64) return ((const long long*)lens_raw)[b];
    return (long long)lens_raw[b];
}

__device__ __forceinline__ short f2bf(float x) {        // RNE fp32 -> bf16 bits
    unsigned u = __float_as_uint(x);
    unsigned r = (u + 0x7FFFu + ((u >> 16) & 1u)) >> 16;
    return (short)r;
}
__device__ __forceinline__ float bf2f(short s) {
    return __uint_as_float(((unsigned)(unsigned short)s) << 16);
}

__device__ __forceinline__ float fast_tanh(float x) {
    // tanh(x) = 1 - 2/(exp(2x)+1); exact saturation at +-inf, branchless
    float e = __expf(2.0f * x);
    return 1.0f - 2.0f / (e + 1.0f);
}

// K0: Wt_hi[a][h], Wt_lo[a][h] = split-bf16 of W[h][a] (transposed so MFMA
// B-fragments are contiguous-K 16B loads). 1 MB total, L2-resident afterwards.
__global__ __launch_bounds__(512) void wsplit_kernel(
    const float* __restrict__ W, short* __restrict__ wt_hi, short* __restrict__ wt_lo)
{
    int a = blockIdx.x;       // 0..511
    int h = threadIdx.x;      // 0..511
    float v = W[(size_t)h * ATTEN + a];
    short hi = f2bf(v);
    short lo = f2bf(v - bf2f(hi));
    wt_hi[(size_t)a * HIDDEN + h] = hi;
    wt_lo[(size_t)a * HIDDEN + h] = lo;
}

// K1: scores[b,s] = sum_a tanh( X[b,s,:]·W[:,a] + bias[a] ) * ctx[a]
// Split-bf16 MFMA GEMM: block = 128 rows x all 512 atten cols, fused epilogue.
__global__ __launch_bounds__(THREADS, 2) void scores_mfma_kernel(
    const float* __restrict__ X,        // [B*S*H] fp32
    const int*   __restrict__ lens_raw,
    const short* __restrict__ wt_hi,    // [A][H] bf16 bits
    const short* __restrict__ wt_lo,
    const float* __restrict__ bias,     // [A]
    const float* __restrict__ ctx,      // [A]
    float* __restrict__ scores)         // [B*S]
{
    __shared__ char lds_raw[2 * BM * BK * 2];   // 64 KB: A-tile hi | lo

    const int tiles_per_b = STEP / BM;  // 16
    int b  = blockIdx.x / tiles_per_b;
    int s0 = (blockIdx.x % tiles_per_b) * BM;
    long long len = load_len(lens_raw, b);
    if ((long long)s0 >= len) return;   // softmax weight 0 for whole tile

    int t = threadIdx.x;
    int wave = t >> 6, lane = t & 63;
    int wrow = wave >> 2, wcol = wave & 3;      // 2 x 4 wave grid
    int l15 = lane & 15, l4 = lane >> 4;

    char* lds_hi = lds_raw;
    char* lds_lo = lds_raw + BM * BK * 2;

    f32x4 acc[4][8];                    // wave tile 64 x 128
#pragma unroll
    for (int mi = 0; mi < 4; ++mi)
#pragma unroll
        for (int ni = 0; ni < 8; ++ni)
            acc[mi][ni] = (f32x4){0.f, 0.f, 0.f, 0.f};

    const int colbase = wcol * 128 + l15;   // this lane's atten column (mod 16)

    for (int kt = 0; kt < HIDDEN / BK; ++kt) {      // 4 K-tiles
        if (kt) __syncthreads();
        // stage X[s0..s0+127][kt*128..+128] as hi/lo bf16, XOR-swizzled
#pragma unroll
        for (int it = 0; it < (BM * BK / 8) / THREADS; ++it) {   // 4
            int c = t + it * THREADS;
            int row  = c >> 4;              // 16 chunks of 8 elems per row
            int slot = c & 15;
            const float* src = X + ((size_t)b * STEP + s0 + row) * HIDDEN
                               + kt * BK + slot * 8;
            float4 x0 = *(const float4*)(src);
            float4 x1 = *(const float4*)(src + 4);
            float xs[8] = {x0.x, x0.y, x0.z, x0.w, x1.x, x1.y, x1.z, x1.w};
            bf16x8 hv, lv;
#pragma unroll
            for (int j = 0; j < 8; ++j) {
                short h = f2bf(xs[j]);
                hv[j] = h;
                lv[j] = f2bf(xs[j] - bf2f(h));
            }
            int off = row * (BK * 2) + ((slot * 16) ^ ((row & 7) << 4));
            *(bf16x8*)(lds_hi + off) = hv;
            *(bf16x8*)(lds_lo + off) = lv;
        }
        __syncthreads();

#pragma unroll
        for (int kk = 0; kk < BK / 32; ++kk) {      // 4 K-steps
            bf16x8 ah[4], al[4];
#pragma unroll
            for (int mi = 0; mi < 4; ++mi) {
                int row = wrow * 64 + mi * 16 + l15;
                int kb  = kk * 64 + l4 * 16;        // byte col = 2*k
                int off = row * (BK * 2) + (kb ^ ((row & 7) << 4));
                ah[mi] = *(const bf16x8*)(lds_hi + off);
                al[mi] = *(const bf16x8*)(lds_lo + off);
            }
            int kglob = kt * BK + kk * 32 + l4 * 8;
#pragma unroll
            for (int ni = 0; ni < 8; ++ni) {
                size_t widx = (size_t)(colbase + ni * 16) * HIDDEN + kglob;
                bf16x8 bh = *(const bf16x8*)(wt_hi + widx);
                bf16x8 bl = *(const bf16x8*)(wt_lo + widx);
#pragma unroll
                for (int mi = 0; mi < 4; ++mi) {
                    acc[mi][ni] = __builtin_amdgcn_mfma_f32_16x16x32_bf16(
                        ah[mi], bh, acc[mi][ni], 0, 0, 0);
                    acc[mi][ni] = __builtin_amdgcn_mfma_f32_16x16x32_bf16(
                        ah[mi], bl, acc[mi][ni], 0, 0, 0);
                    acc[mi][ni] = __builtin_amdgcn_mfma_f32_16x16x32_bf16(
                        al[mi], bh, acc[mi][ni], 0, 0, 0);
                }
            }
        }
    }

    // fused epilogue: tanh(acc+bias)*ctx, reduce over all 512 cols
    float bi[8], ci[8];
#pragma unroll
    for (int ni = 0; ni < 8; ++ni) {
        int a = colbase + ni * 16;
        bi[ni] = bias[a];
        ci[ni] = ctx[a];
    }
    __syncthreads();                        // done reading A-tile LDS
    float* partial = (float*)lds_raw;       // [4 wcol][BM]
#pragma unroll
    for (int mi = 0; mi < 4; ++mi) {
#pragma unroll
        for (int reg = 0; reg < 4; ++reg) {
            float s = 0.f;
#pragma unroll
            for (int ni = 0; ni < 8; ++ni)
                s += fast_tanh(acc[mi][ni][reg] + bi[ni]) * ci[ni];
            // reduce over the 16 lanes sharing this output row
            s += __shfl_xor(s, 1);
            s += __shfl_xor(s, 2);
            s += __shfl_xor(s, 4);
            s += __shfl_xor(s, 8);
            if (l15 == 0) {
                int row = wrow * 64 + mi * 16 + l4 * 4 + reg;  // C/D: row=(l>>4)*4+reg
                partial[wcol * BM + row] = s;
            }
        }
    }
    __syncthreads();
    if (t < BM) {
        float v = partial[0 * BM + t] + partial[1 * BM + t]
                + partial[2 * BM + t] + partial[3 * BM + t];
        scores[(size_t)b * STEP + s0 + t] = v;
    }
}

// K2: masked softmax per batch row (deterministic tree reductions)
__global__ __launch_bounds__(256) void softmax_kernel(
    const float* __restrict__ scores, const int* __restrict__ lens_raw,
    float* __restrict__ atten)
{
    __shared__ float wmax[4], wsum[4];
    int b = blockIdx.x;
    long long len = load_len(lens_raw, b);
    int t = threadIdx.x;
    const float* srow = scores + (size_t)b * STEP;
    float* arow = atten + (size_t)b * STEP;

    float sv[STEP / 256];
    float locmax = -INFINITY;
#pragma unroll
    for (int k = 0; k < 8; ++k) {
        int s = t + k * 256;
        float v = ((long long)s < len) ? srow[s] : -INFINITY;
        sv[k] = v;
        locmax = fmaxf(locmax, v);
    }
    for (int o = 1; o < 64; o <<= 1) locmax = fmaxf(locmax, __shfl_xor(locmax, o));
    int wave = t >> 6, lane = t & 63;
    if (lane == 0) wmax[wave] = locmax;
    __syncthreads();
    float gmax = fmaxf(fmaxf(wmax[0], wmax[1]), fmaxf(wmax[2], wmax[3]));

    float ev[8];
    float locsum = 0.f;
#pragma unroll
    for (int k = 0; k < 8; ++k) {
        float e = (sv[k] == -INFINITY) ? 0.f : expf(sv[k] - gmax);
        ev[k] = e;
        locsum += e;
    }
    for (int o = 1; o < 64; o <<= 1) locsum += __shfl_xor(locsum, o);
    if (lane == 0) wsum[wave] = locsum;
    __syncthreads();
    float inv = 1.f / (wsum[0] + wsum[1] + wsum[2] + wsum[3]);
#pragma unroll
    for (int k = 0; k < 8; ++k) {
        int s = t + k * 256;
        arow[s] = ev[k] * inv;    // padded positions get exact 0
    }
}

// K3a: partial[b,ch,h] = sum_{s in chunk, s<len} atten[b,s] * X[b,s,h]
__global__ __launch_bounds__(256) void wsum_kernel(
    const float* __restrict__ X, const int* __restrict__ lens_raw,
    const float* __restrict__ atten, float* __restrict__ partial)
{
    int ch = blockIdx.x;
    int b  = blockIdx.y;
    long long len = load_len(lens_raw, b);
    int t = threadIdx.x;
    int s0 = ch * CHS;
    long long send_ll = (long long)(s0 + CHS);
    if (send_ll > len) send_ll = len;
    int send = (int)send_ll;

    const float* arow = atten + (size_t)b * STEP;
    float acc0 = 0.f, acc1 = 0.f;
    for (int s = s0; s < send; ++s) {
        float a = arow[s];
        const float* xr = X + ((size_t)b * STEP + s) * HIDDEN;
        acc0 = fmaf(a, xr[t], acc0);
        acc1 = fmaf(a, xr[t + 256], acc1);
    }
    float* prow = partial + ((size_t)b * NCH + ch) * HIDDEN;
    prow[t] = acc0;            // skipped chunks write zeros
    prow[t + 256] = acc1;
}

// K3b: out[b,h] = sum_ch partial[b,ch,h]
__global__ __launch_bounds__(256) void finalize_kernel(
    const float* __restrict__ partial, float* __restrict__ out)
{
    int b = blockIdx.x;
    int t = threadIdx.x;
    float a0 = 0.f, a1 = 0.f;
#pragma unroll
    for (int ch = 0; ch < NCH; ++ch) {
        const float* prow = partial + ((size_t)b * NCH + ch) * HIDDEN;
        a0 += prow[t];
        a1 += prow[t + 256];
    }
    out[(size_t)b * HIDDEN + t] = a0;
    out[(size_t)b * HIDDEN + t + 256] = a1;
}

extern "C" void kernel_launch(void* const* d_in, const int* in_sizes, int n_in,
                              void* d_out, int out_size, void* d_ws, size_t ws_size,
                              hipStream_t stream) {
    const float* X    = (const float*)d_in[0];
    const int*   lens = (const int*)d_in[1];   // dtype sniffed on device
    const float* W    = (const float*)d_in[2];
    const float* bias = (const float*)d_in[3];
    const float* ctx  = (const float*)d_in[4];
    float* out = (float*)d_out;

    char* ws = (char*)d_ws;
    float* scores  = (float*)ws;                              // 256 KB
    float* atten   = (float*)(ws + 256 * 1024);               // 256 KB
    float* partial = (float*)(ws + 512 * 1024);               // 1 MB
    short* wt_hi   = (short*)(ws + 512 * 1024 + 1024 * 1024); // 512 KB
    short* wt_lo   = (short*)(ws + 512 * 1024 + 1536 * 1024); // 512 KB

    wsplit_kernel<<<dim3(ATTEN), 512, 0, stream>>>(W, wt_hi, wt_lo);
    scores_mfma_kernel<<<dim3(BATCH * (STEP / BM)), THREADS, 0, stream>>>(
        X, lens, wt_hi, wt_lo, bias, ctx, scores);
    softmax_kernel<<<dim3(BATCH), 256, 0, stream>>>(scores, lens, atten);
    wsum_kernel<<<dim3(NCH, BATCH), 256, 0, stream>>>(X, lens, atten, partial);
    finalize_kernel<<<dim3(BATCH), 256, 0, stream>>>(partial, out);
}